// Round 1
// baseline (1956.714 us; speedup 1.0000x reference)
//
#include <hip/hip_runtime.h>

// Problem constants (fixed by the reference file)
#define NNODES 50000
#define NEDGES 1600000
#define CE 64
#define CN 256
#define COUT 256
#define KTOT (CE + CN)   // 320

// ---------------------------------------------------------------------------
// Kernel 1: scatter-add edge features into A (NNODES x CE) with fp32 atomics.
// One thread handles 4 channels (float4 load), 16 threads per edge.
// ---------------------------------------------------------------------------
__global__ __launch_bounds__(256) void scatter_kernel(
    const float4* __restrict__ ea4,   // edge_attr viewed as (E*16) float4
    const int* __restrict__ row_idx,
    float* __restrict__ A)
{
    int tid = blockIdx.x * 256 + threadIdx.x;   // E*16 threads exactly
    int e = tid >> 4;
    int q = tid & 15;
    float4 v = ea4[tid];
    int r = row_idx[e];
    float* dst = &A[r * CE + q * 4];
    atomicAdd(dst + 0, v.x);
    atomicAdd(dst + 1, v.y);
    atomicAdd(dst + 2, v.z);
    atomicAdd(dst + 3, v.w);
}

// ---------------------------------------------------------------------------
// Kernel 2: out = relu( [A/D | X] @ [W_pass ; W_self] + b_pass + b_self )
// fp32 tiled GEMM: BM=64 x BN=64 tile, BK=16, 256 threads, 4x4 reg blocking.
// K = 320 (first 64 from A/D + W_pass, remaining 256 from X + W_self).
// ---------------------------------------------------------------------------
#define BM 64
#define BN 64
#define BK 16

__global__ __launch_bounds__(256) void fused_gemm_kernel(
    const float* __restrict__ A,    // NNODES x CE (unnormalized sums)
    const float* __restrict__ D,    // NNODES
    const float* __restrict__ X,    // NNODES x CN
    const float* __restrict__ Wp,   // CE x COUT
    const float* __restrict__ bp,   // COUT
    const float* __restrict__ Ws,   // CN x COUT
    const float* __restrict__ bs,   // COUT
    float* __restrict__ out)        // NNODES x COUT
{
    __shared__ float sA[BK][BM + 4];   // [k][m], +4 keeps 16B alignment, kills conflicts
    __shared__ float sB[BK][BN + 4];   // [k][n]

    const int tid = threadIdx.x;        // 0..255
    const int row0 = blockIdx.x * BM;
    const int col0 = blockIdx.y * BN;
    const int tx = tid & 15;            // output-col group
    const int ty = tid >> 4;            // output-row group

    float acc[4][4] = {};

    for (int k0 = 0; k0 < KTOT; k0 += BK) {
        // --- stage A-tile (64 rows x 16 k) ---
        // linear l = tid + i*256 ; kk = l%16 (fast-varying -> coalesced k), m = l/16
        #pragma unroll
        for (int i = 0; i < 4; ++i) {
            int l  = tid + i * 256;
            int kk = l & 15;
            int m  = l >> 4;
            int n  = row0 + m;
            int k  = k0 + kk;
            float v = 0.f;
            if (n < NNODES) {
                if (k < CE) v = A[n * CE + k] / D[n];
                else        v = X[n * CN + (k - CE)];
            }
            sA[kk][m] = v;
        }
        // --- stage B-tile (16 k x 64 cols) ---
        #pragma unroll
        for (int i = 0; i < 4; ++i) {
            int l  = tid + i * 256;
            int n  = l & 63;
            int kk = l >> 6;
            int k  = k0 + kk;
            int j  = col0 + n;
            float v = (k < CE) ? Wp[k * COUT + j] : Ws[(k - CE) * COUT + j];
            sB[kk][n] = v;
        }
        __syncthreads();

        #pragma unroll
        for (int kk = 0; kk < BK; ++kk) {
            float a[4], b[4];
            #pragma unroll
            for (int i = 0; i < 4; ++i) a[i] = sA[kk][ty * 4 + i];
            #pragma unroll
            for (int j = 0; j < 4; ++j) b[j] = sB[kk][tx * 4 + j];
            #pragma unroll
            for (int i = 0; i < 4; ++i)
                #pragma unroll
                for (int j = 0; j < 4; ++j)
                    acc[i][j] = fmaf(a[i], b[j], acc[i][j]);
        }
        __syncthreads();
    }

    // --- epilogue: + b_pass + b_self, relu, float4 store ---
    const int col = col0 + tx * 4;
    float4 bias;
    bias.x = bp[col + 0] + bs[col + 0];
    bias.y = bp[col + 1] + bs[col + 1];
    bias.z = bp[col + 2] + bs[col + 2];
    bias.w = bp[col + 3] + bs[col + 3];
    #pragma unroll
    for (int i = 0; i < 4; ++i) {
        int n = row0 + ty * 4 + i;
        if (n >= NNODES) continue;
        float4 o;
        o.x = fmaxf(acc[i][0] + bias.x, 0.f);
        o.y = fmaxf(acc[i][1] + bias.y, 0.f);
        o.z = fmaxf(acc[i][2] + bias.z, 0.f);
        o.w = fmaxf(acc[i][3] + bias.w, 0.f);
        *(float4*)&out[n * COUT + col] = o;
    }
}

extern "C" void kernel_launch(void* const* d_in, const int* in_sizes, int n_in,
                              void* d_out, int out_size, void* d_ws, size_t ws_size,
                              hipStream_t stream) {
    const float* D         = (const float*)d_in[0];
    const int*   row_idx   = (const int*)  d_in[1];
    const float* edge_attr = (const float*)d_in[2];
    const float* X         = (const float*)d_in[3];
    const float* W_pass    = (const float*)d_in[4];
    const float* b_pass    = (const float*)d_in[5];
    const float* W_self    = (const float*)d_in[6];
    const float* b_self    = (const float*)d_in[7];
    float* out = (float*)d_out;

    float* A = (float*)d_ws;   // NNODES x CE accumulator (12.8 MB)

    // zero the segment-sum accumulator (ws is poisoned before every launch)
    hipMemsetAsync(A, 0, (size_t)NNODES * CE * sizeof(float), stream);

    // scatter: E*16 threads, 256/block
    scatter_kernel<<<dim3(NEDGES * 16 / 256), dim3(256), 0, stream>>>(
        (const float4*)edge_attr, row_idx, A);

    // fused GEMM: grid over (row tiles, col tiles)
    dim3 grid((NNODES + BM - 1) / BM, COUT / BN);
    fused_gemm_kernel<<<grid, dim3(256), 0, stream>>>(
        A, D, X, W_pass, b_pass, W_self, b_self, out);
}

// Round 2
// 935.860 us; speedup vs baseline: 2.0908x; 2.0908x over previous
//
#include <hip/hip_runtime.h>

// Problem constants (fixed by the reference file)
#define NNODES 50000
#define NEDGES 1600000
#define CE 64
#define CN 256
#define COUT 256
#define KTOT (CE + CN)   // 320
#define BCAP 64          // bucket capacity per node (Poisson(32); overflow -> atomic fallback)

// ---------------------------------------------------------------------------
// Kernel 1: bucket fill. One thread per edge. pos = atomicAdd(count[r]) gives
// both degree and slot. Overflow edges (astronomically rare) fall back to
// direct fp32 atomics into (zeroed) A, keeping correctness unconditional.
// ---------------------------------------------------------------------------
__global__ __launch_bounds__(256) void fill_kernel(
    const int* __restrict__ row_idx,
    const float* __restrict__ ea,
    int* __restrict__ counts,
    int* __restrict__ buckets,
    float* __restrict__ A)
{
    int e = blockIdx.x * 256 + threadIdx.x;   // exactly NEDGES threads
    int r = row_idx[e];
    int pos = atomicAdd(&counts[r], 1);
    if (pos < BCAP) {
        buckets[r * BCAP + pos] = e;
    } else {
        for (int c = 0; c < CE; ++c)
            atomicAdd(&A[r * CE + c], ea[e * CE + c]);
    }
}

// ---------------------------------------------------------------------------
// Kernel 2: gather. One wave per node. Lane layout: sub = lane/16 picks one of
// 4 edges processed concurrently; c4 = lane%16 picks a float4 of channels.
// Each iteration: 4 edges x 256B = 1KB fully-coalesced load per wave.
// Butterfly-reduce across sub groups, add overflow contributions from A,
// normalize by 1/D, store A (now holding A_sum/D).
// ---------------------------------------------------------------------------
__global__ __launch_bounds__(256) void gather_kernel(
    const float4* __restrict__ ea4,    // edge_attr as (E*16) float4
    const int* __restrict__ counts,
    const int* __restrict__ buckets,
    const float* __restrict__ D,
    float4* __restrict__ A4)           // in: overflow sums; out: normalized
{
    const int wave = threadIdx.x >> 6;
    const int lane = threadIdx.x & 63;
    const int n = blockIdx.x * 4 + wave;      // 12500 * 4 == NNODES exactly
    const int sub = lane >> 4;
    const int c4  = lane & 15;

    int deg = counts[n];
    if (deg > BCAP) deg = BCAP;

    float4 acc = make_float4(0.f, 0.f, 0.f, 0.f);
    const int* bkt = &buckets[n * BCAP];
    int i = 0;
    for (; i + 4 <= deg; i += 4) {
        int e = bkt[i + sub];
        float4 v = ea4[e * 16 + c4];
        acc.x += v.x; acc.y += v.y; acc.z += v.z; acc.w += v.w;
    }
    if (i + sub < deg) {
        int e = bkt[i + sub];
        float4 v = ea4[e * 16 + c4];
        acc.x += v.x; acc.y += v.y; acc.z += v.z; acc.w += v.w;
    }
    // reduce across the 4 sub groups (lanes xor 16, xor 32)
    acc.x += __shfl_xor(acc.x, 16); acc.x += __shfl_xor(acc.x, 32);
    acc.y += __shfl_xor(acc.y, 16); acc.y += __shfl_xor(acc.y, 32);
    acc.z += __shfl_xor(acc.z, 16); acc.z += __shfl_xor(acc.z, 32);
    acc.w += __shfl_xor(acc.w, 16); acc.w += __shfl_xor(acc.w, 32);

    if (sub == 0) {
        float invd = 1.0f / D[n];
        float4 prev = A4[n * 16 + c4];        // overflow contributions (usually 0)
        float4 o;
        o.x = (acc.x + prev.x) * invd;
        o.y = (acc.y + prev.y) * invd;
        o.z = (acc.z + prev.z) * invd;
        o.w = (acc.w + prev.w) * invd;
        A4[n * 16 + c4] = o;
    }
}

// ---------------------------------------------------------------------------
// Kernel 3: out = relu( [Anorm | X] @ [W_pass ; W_self] + b_pass + b_self )
// BM=128 x BN=64 tile, BK=16, 256 threads, 8x4 register tile, float4 LDS reads.
// ---------------------------------------------------------------------------
#define BM 128
#define BN 64
#define BK 16

__global__ __launch_bounds__(256) void fused_gemm_kernel(
    const float* __restrict__ Anorm,  // NNODES x CE, already /D
    const float* __restrict__ X,      // NNODES x CN
    const float* __restrict__ Wp,     // CE x COUT
    const float* __restrict__ bp,     // COUT
    const float* __restrict__ Ws,     // CN x COUT
    const float* __restrict__ bs,     // COUT
    float* __restrict__ out)          // NNODES x COUT
{
    __shared__ float sA[BK][BM + 4];   // [k][m]; row stride 132 floats (16B aligned)
    __shared__ float sB[BK][BN + 4];   // [k][n]; row stride 68 floats (16B aligned)

    const int tid = threadIdx.x;        // 0..255
    const int row0 = blockIdx.x * BM;
    const int col0 = blockIdx.y * BN;
    const int tx = tid & 15;            // 4-col group
    const int ty = tid >> 4;            // 8-row group (0..15)

    float acc[8][4] = {};

    for (int k0 = 0; k0 < KTOT; k0 += BK) {
        // --- stage A-tile (128 rows x 16 k) ---
        #pragma unroll
        for (int i = 0; i < 8; ++i) {
            int l  = tid + i * 256;
            int kk = l & 15;
            int m  = l >> 4;
            int n  = row0 + m;
            int k  = k0 + kk;
            float v = 0.f;
            if (n < NNODES)
                v = (k < CE) ? Anorm[n * CE + k] : X[n * CN + (k - CE)];
            sA[kk][m] = v;
        }
        // --- stage B-tile (16 k x 64 cols) ---
        #pragma unroll
        for (int i = 0; i < 4; ++i) {
            int l  = tid + i * 256;
            int nn = l & 63;
            int kk = l >> 6;
            int k  = k0 + kk;
            int j  = col0 + nn;
            sB[kk][nn] = (k < CE) ? Wp[k * COUT + j] : Ws[(k - CE) * COUT + j];
        }
        __syncthreads();

        #pragma unroll
        for (int kk = 0; kk < BK; ++kk) {
            float4 a0 = *(const float4*)&sA[kk][ty * 8 + 0];
            float4 a1 = *(const float4*)&sA[kk][ty * 8 + 4];
            float4 b  = *(const float4*)&sB[kk][tx * 4];
            float a[8] = {a0.x, a0.y, a0.z, a0.w, a1.x, a1.y, a1.z, a1.w};
            float bb[4] = {b.x, b.y, b.z, b.w};
            #pragma unroll
            for (int i = 0; i < 8; ++i)
                #pragma unroll
                for (int j = 0; j < 4; ++j)
                    acc[i][j] = fmaf(a[i], bb[j], acc[i][j]);
        }
        __syncthreads();
    }

    // --- epilogue ---
    const int col = col0 + tx * 4;
    float4 bias;
    bias.x = bp[col + 0] + bs[col + 0];
    bias.y = bp[col + 1] + bs[col + 1];
    bias.z = bp[col + 2] + bs[col + 2];
    bias.w = bp[col + 3] + bs[col + 3];
    #pragma unroll
    for (int i = 0; i < 8; ++i) {
        int n = row0 + ty * 8 + i;
        if (n >= NNODES) continue;
        float4 o;
        o.x = fmaxf(acc[i][0] + bias.x, 0.f);
        o.y = fmaxf(acc[i][1] + bias.y, 0.f);
        o.z = fmaxf(acc[i][2] + bias.z, 0.f);
        o.w = fmaxf(acc[i][3] + bias.w, 0.f);
        *(float4*)&out[n * COUT + col] = o;
    }
}

extern "C" void kernel_launch(void* const* d_in, const int* in_sizes, int n_in,
                              void* d_out, int out_size, void* d_ws, size_t ws_size,
                              hipStream_t stream) {
    const float* D         = (const float*)d_in[0];
    const int*   row_idx   = (const int*)  d_in[1];
    const float* edge_attr = (const float*)d_in[2];
    const float* X         = (const float*)d_in[3];
    const float* W_pass    = (const float*)d_in[4];
    const float* b_pass    = (const float*)d_in[5];
    const float* W_self    = (const float*)d_in[6];
    const float* b_self    = (const float*)d_in[7];
    float* out = (float*)d_out;

    // workspace layout (25.8 MB total)
    char* ws = (char*)d_ws;
    float* A      = (float*)ws;                            // 50000*64 f32 = 12.8 MB
    int*   counts = (int*)(ws + (size_t)NNODES * CE * 4);  // 50000 i32   = 0.2 MB
    int*   buckets= (int*)(ws + (size_t)NNODES * CE * 4 + (size_t)NNODES * 4); // 12.8 MB

    hipMemsetAsync(A, 0, (size_t)NNODES * CE * sizeof(float), stream);   // overflow target
    hipMemsetAsync(counts, 0, (size_t)NNODES * sizeof(int), stream);

    fill_kernel<<<dim3(NEDGES / 256), dim3(256), 0, stream>>>(
        row_idx, edge_attr, counts, buckets, A);

    gather_kernel<<<dim3(NNODES / 4), dim3(256), 0, stream>>>(
        (const float4*)edge_attr, counts, buckets, D, (float4*)A);

    dim3 grid((NNODES + BM - 1) / BM, COUT / BN);
    fused_gemm_kernel<<<grid, dim3(256), 0, stream>>>(
        A, X, W_pass, b_pass, W_self, b_self, out);
}

// Round 3
// 784.196 us; speedup vs baseline: 2.4952x; 1.1934x over previous
//
#include <hip/hip_runtime.h>
#include <hip/hip_bf16.h>

// Problem constants (fixed by the reference file)
#define NNODES 50000
#define NEDGES 1600000
#define CE 64
#define CN 256
#define COUT 256
#define KTOT (CE + CN)   // 320
#define BCAP 64          // bucket capacity per node (Poisson(32); overflow -> atomic fallback)

typedef __attribute__((ext_vector_type(8))) short bf16x8;
typedef __attribute__((ext_vector_type(4))) float f32x4;

__device__ inline ushort f2bf(float f) {
    __hip_bfloat16 h = __float2bfloat16(f);
    return *(ushort*)&h;
}

// ---------------------------------------------------------------------------
// Kernel 1: bucket fill. One thread per edge. pos = atomicAdd(count[r]) gives
// both degree and slot. Overflow edges (rare) fall back to fp32 atomics into
// zeroed Aovf, keeping correctness unconditional.
// ---------------------------------------------------------------------------
__global__ __launch_bounds__(256) void fill_kernel(
    const int* __restrict__ row_idx,
    const float* __restrict__ ea,
    int* __restrict__ counts,
    int* __restrict__ buckets,
    float* __restrict__ Aovf)
{
    int e = blockIdx.x * 256 + threadIdx.x;   // exactly NEDGES threads
    int r = row_idx[e];
    int pos = atomicAdd(&counts[r], 1);
    if (pos < BCAP) {
        buckets[r * BCAP + pos] = e;
    } else {
        for (int c = 0; c < CE; ++c)
            atomicAdd(&Aovf[r * CE + c], ea[e * CE + c]);
    }
}

// ---------------------------------------------------------------------------
// Kernel 2: prep. Transpose [W_pass; W_self] (320x256 fp32) into bf16
// Wt[n][k] (n-major, k contiguous) and fuse biases. 320 blocks x 256 thr.
// ---------------------------------------------------------------------------
__global__ __launch_bounds__(256) void prep_kernel(
    const float* __restrict__ Wp, const float* __restrict__ Ws,
    const float* __restrict__ bp, const float* __restrict__ bs,
    ushort* __restrict__ Wt, float* __restrict__ bias)
{
    int k = blockIdx.x;          // 0..319
    int n = threadIdx.x;         // 0..255
    float v = (k < CE) ? Wp[k * COUT + n] : Ws[(k - CE) * COUT + n];
    Wt[n * KTOT + k] = f2bf(v);
    if (k == 0) bias[n] = bp[n] + bs[n];
}

// ---------------------------------------------------------------------------
// Kernel 3: gather. One wave per node; sub = lane/16 picks one of 4 edges per
// iteration, c4 = lane%16 picks a float4 of channels (256B coalesced / edge).
// Butterfly-reduce, add overflow sums, normalize by 1/D, emit bf16 A.
// ---------------------------------------------------------------------------
__global__ __launch_bounds__(256) void gather_kernel(
    const float4* __restrict__ ea4,    // edge_attr as (E*16) float4
    const int* __restrict__ counts,
    const int* __restrict__ buckets,
    const float* __restrict__ D,
    const float4* __restrict__ Aovf4,  // overflow sums (usually 0)
    ushort* __restrict__ Abf)          // out: NNODES x CE bf16, normalized
{
    const int wave = threadIdx.x >> 6;
    const int lane = threadIdx.x & 63;
    const int n = blockIdx.x * 4 + wave;      // 12500 * 4 == NNODES exactly
    const int sub = lane >> 4;
    const int c4  = lane & 15;

    int deg = counts[n];
    if (deg > BCAP) deg = BCAP;

    float4 acc = make_float4(0.f, 0.f, 0.f, 0.f);
    const int* bkt = &buckets[n * BCAP];
    int i = 0;
    for (; i + 4 <= deg; i += 4) {
        int e = bkt[i + sub];
        float4 v = ea4[e * 16 + c4];
        acc.x += v.x; acc.y += v.y; acc.z += v.z; acc.w += v.w;
    }
    if (i + sub < deg) {
        int e = bkt[i + sub];
        float4 v = ea4[e * 16 + c4];
        acc.x += v.x; acc.y += v.y; acc.z += v.z; acc.w += v.w;
    }
    acc.x += __shfl_xor(acc.x, 16); acc.x += __shfl_xor(acc.x, 32);
    acc.y += __shfl_xor(acc.y, 16); acc.y += __shfl_xor(acc.y, 32);
    acc.z += __shfl_xor(acc.z, 16); acc.z += __shfl_xor(acc.z, 32);
    acc.w += __shfl_xor(acc.w, 16); acc.w += __shfl_xor(acc.w, 32);

    if (sub == 0) {
        float invd = 1.0f / D[n];
        float4 prev = Aovf4[n * 16 + c4];
        ushort4 o;
        o.x = f2bf((acc.x + prev.x) * invd);
        o.y = f2bf((acc.y + prev.y) * invd);
        o.z = f2bf((acc.z + prev.z) * invd);
        o.w = f2bf((acc.w + prev.w) * invd);
        *(ushort4*)&Abf[n * CE + c4 * 4] = o;   // 8B aligned
    }
}

// ---------------------------------------------------------------------------
// Kernel 4: MFMA bf16 GEMM. out = relu([Abf | bf16(X)] @ Wt^T + bias)
// 128x128 tile, BK=32, 256 threads (4 waves, each a 64x64 quadrant of
// 4x4 mfma_f32_16x16x32_bf16). LDS rows padded +8 bf16: fragment
// ds_read_b128 lands at 2-way bank aliasing (free).
// ---------------------------------------------------------------------------
#define GBM 128
#define GBN 128
#define GBK 32
#define APAD 8

__global__ __launch_bounds__(256) void mfma_gemm_kernel(
    const ushort* __restrict__ Abf,   // NNODES x CE bf16 (normalized)
    const float* __restrict__ X,      // NNODES x CN fp32
    const ushort* __restrict__ Wt,    // COUT x KTOT bf16 (n-major)
    const float* __restrict__ bias,   // COUT fp32 (bp+bs)
    float* __restrict__ out)          // NNODES x COUT
{
    __shared__ ushort sA[GBM][GBK + APAD];   // [m][k], k contiguous
    __shared__ ushort sB[GBN][GBK + APAD];   // [n][k], k contiguous

    const int tid  = threadIdx.x;
    const int row0 = blockIdx.x * GBM;
    const int col0 = blockIdx.y * GBN;
    const int wave = tid >> 6;
    const int lane = tid & 63;
    const int m16  = lane & 15;
    const int kg   = lane >> 4;              // quad 0..3
    const int wr   = (wave >> 1) * 64;       // wave row offset in tile
    const int wc   = (wave & 1) * 64;        // wave col offset in tile

    const int sr = tid >> 1;                 // staging row/col 0..127
    const int sh = tid & 1;                  // staging k-half (16 elems)

    f32x4 acc[4][4];
    #pragma unroll
    for (int i = 0; i < 4; ++i)
        #pragma unroll
        for (int j = 0; j < 4; ++j)
            acc[i][j] = (f32x4){0.f, 0.f, 0.f, 0.f};

    for (int k0 = 0; k0 < KTOT; k0 += GBK) {
        // --- stage A-tile: 128 rows x 32 k; each thread 16 contiguous k ---
        {
            int gn = row0 + sr;
            uint4 v0 = {0,0,0,0}, v1 = {0,0,0,0};
            if (k0 < CE) {
                if (gn < NNODES) {
                    const uint4* src = (const uint4*)(Abf + gn * CE + k0 + sh * 16);
                    v0 = src[0]; v1 = src[1];
                }
            } else {
                if (gn < NNODES) {
                    const float4* xs = (const float4*)(X + (size_t)gn * CN + (k0 - CE) + sh * 16);
                    float4 a = xs[0], b = xs[1], c = xs[2], d = xs[3];
                    union { ushort us[8]; uint4 u; } p0, p1;
                    p0.us[0]=f2bf(a.x); p0.us[1]=f2bf(a.y); p0.us[2]=f2bf(a.z); p0.us[3]=f2bf(a.w);
                    p0.us[4]=f2bf(b.x); p0.us[5]=f2bf(b.y); p0.us[6]=f2bf(b.z); p0.us[7]=f2bf(b.w);
                    p1.us[0]=f2bf(c.x); p1.us[1]=f2bf(c.y); p1.us[2]=f2bf(c.z); p1.us[3]=f2bf(c.w);
                    p1.us[4]=f2bf(d.x); p1.us[5]=f2bf(d.y); p1.us[6]=f2bf(d.z); p1.us[7]=f2bf(d.w);
                    v0 = p0.u; v1 = p1.u;
                }
            }
            *(uint4*)&sA[sr][sh * 16]     = v0;
            *(uint4*)&sA[sr][sh * 16 + 8] = v1;
        }
        // --- stage B-tile: 128 cols x 32 k from Wt (bf16, k contiguous) ---
        {
            const uint4* src = (const uint4*)(Wt + (size_t)(col0 + sr) * KTOT + k0 + sh * 16);
            *(uint4*)&sB[sr][sh * 16]     = src[0];
            *(uint4*)&sB[sr][sh * 16 + 8] = src[1];
        }
        __syncthreads();

        bf16x8 aF[4], bF[4];
        #pragma unroll
        for (int i = 0; i < 4; ++i)
            aF[i] = *(const bf16x8*)&sA[wr + i * 16 + m16][kg * 8];
        #pragma unroll
        for (int j = 0; j < 4; ++j)
            bF[j] = *(const bf16x8*)&sB[wc + j * 16 + m16][kg * 8];
        #pragma unroll
        for (int i = 0; i < 4; ++i)
            #pragma unroll
            for (int j = 0; j < 4; ++j)
                acc[i][j] = __builtin_amdgcn_mfma_f32_16x16x32_bf16(aF[i], bF[j], acc[i][j], 0, 0, 0);
        __syncthreads();
    }

    // --- epilogue: D layout col=lane&15, row=quad*4+reg ---
    #pragma unroll
    for (int j = 0; j < 4; ++j) {
        int col = col0 + wc + j * 16 + m16;
        float bv = bias[col];
        #pragma unroll
        for (int i = 0; i < 4; ++i) {
            int rbase = row0 + wr + i * 16 + kg * 4;
            #pragma unroll
            for (int t = 0; t < 4; ++t) {
                int row = rbase + t;
                if (row < NNODES)
                    out[(size_t)row * COUT + col] = fmaxf(acc[i][j][t] + bv, 0.f);
            }
        }
    }
}

extern "C" void kernel_launch(void* const* d_in, const int* in_sizes, int n_in,
                              void* d_out, int out_size, void* d_ws, size_t ws_size,
                              hipStream_t stream) {
    const float* D         = (const float*)d_in[0];
    const int*   row_idx   = (const int*)  d_in[1];
    const float* edge_attr = (const float*)d_in[2];
    const float* X         = (const float*)d_in[3];
    const float* W_pass    = (const float*)d_in[4];
    const float* b_pass    = (const float*)d_in[5];
    const float* W_self    = (const float*)d_in[6];
    const float* b_self    = (const float*)d_in[7];
    float* out = (float*)d_out;

    // workspace layout (~32.4 MB of the ~1.6 GB ws)
    char* ws = (char*)d_ws;
    size_t off = 0;
    float* Aovf   = (float*)(ws + off); off += (size_t)NNODES * CE * 4;        // 12.8 MB
    int*   counts = (int*)  (ws + off); off += (size_t)NNODES * 4;             // 0.2 MB
    int*   buckets= (int*)  (ws + off); off += (size_t)NNODES * BCAP * 4;      // 12.8 MB
    ushort* Abf   = (ushort*)(ws + off); off += (size_t)NNODES * CE * 2;       // 6.4 MB
    ushort* Wt    = (ushort*)(ws + off); off += (size_t)COUT * KTOT * 2;       // 160 KB
    float* bias   = (float*)(ws + off); off += (size_t)COUT * 4;

    hipMemsetAsync(Aovf, 0, (size_t)NNODES * CE * sizeof(float), stream);
    hipMemsetAsync(counts, 0, (size_t)NNODES * sizeof(int), stream);

    fill_kernel<<<dim3(NEDGES / 256), dim3(256), 0, stream>>>(
        row_idx, edge_attr, counts, buckets, Aovf);

    prep_kernel<<<dim3(KTOT), dim3(256), 0, stream>>>(
        W_pass, W_self, b_pass, b_self, Wt, bias);

    gather_kernel<<<dim3(NNODES / 4), dim3(256), 0, stream>>>(
        (const float4*)edge_attr, counts, buckets, D, (const float4*)Aovf, Abf);

    dim3 grid((NNODES + GBM - 1) / GBM, COUT / GBN);
    mfma_gemm_kernel<<<grid, dim3(256), 0, stream>>>(
        Abf, X, Wt, bias, out);
}